// Round 11
// baseline (886.455 us; speedup 1.0000x reference)
//
#include <hip/hip_runtime.h>
#include <stdint.h>

#define NB 2048
#define OBSD 256
#define POP 10
#define NIN 2560       // OBS_DIM * POP_DIM
#define H 256          // HID1 == HID2
#define OUTP 80        // ACT_DIM * DE_POP
#define TS 25

// correctly-rounded fp32 exp (fp64 exp then round) — matches SVML high-accuracy
// expf that numpy dispatches to on AVX512 hosts (validated r8: absmax 4.8e-7).
__device__ __forceinline__ float exp_cr(float x) {
    return (float)exp((double)x);
}

// ---------------- K0: transpose weights into fp32 [k][n] layouts in ws ----------------
__global__ __launch_bounds__(256) void k0_transpose(
    const float* __restrict__ w1, const float* __restrict__ w2, const float* __restrict__ w3,
    float* __restrict__ w1t, float* __restrict__ w2t, float* __restrict__ w3t)
{
    int idx = blockIdx.x * 256 + threadIdx.x;
    const int N1 = NIN * H;       // 655360
    const int N2 = H * H;         // 65536
    const int N3 = H * OUTP;      // 20480
    if (idx < N1) {
        int i = idx >> 8, j = idx & 255;
        w1t[idx] = w1[j * NIN + i];
    } else if (idx < N1 + N2) {
        int k = idx - N1;
        int i = k >> 8, j = k & 255;
        w2t[k] = w2[j * H + i];
    } else if (idx < N1 + N2 + N3) {
        int k = idx - N1 - N2;
        int i = k / OUTP, j = k - i * OUTP;
        w3t[k] = w3[j * H + i];
    }
}

// One LIF step, numpy-faithful per-op rounding (no contraction):
// c' = ((c*0.5) + x) + b ; v = ((vp*0.75)*(1-s)) + c' ;
// vth = 0.25 + 0.5*(exp((vp-v)/3) - 1) ; s' = (v > vth)
__device__ __forceinline__ void lif_step(float x, float bv, float& c, float& v, float& s) {
    float cn = __fadd_rn(__fadd_rn(__fmul_rn(c, 0.5f), x), bv);
    c = cn;
    float vp = v;
    float t  = __fmul_rn(__fmul_rn(vp, 0.75f), __fadd_rn(1.0f, -s));
    float vn = __fadd_rn(t, cn);
    float ag = __fdiv_rn(__fadd_rn(vp, -vn), 3.0f);
    float ex = exp_cr(ag);
    float vth = __fadd_rn(0.25f, __fmul_rn(0.5f, __fadd_rn(ex, -1.0f)));
    v = vn;
    s = (vn > vth) ? 1.0f : 0.0f;
}

// ---------------- K1: fused, ONE batch row per block (2048 blocks) ----------------
// Thread tid owns hidden neuron tid end-to-end; threads 0..79 own layer-3
// neurons. All 25 timesteps of each layer are computed before the next layer:
// the inter-layer data is just 25-bit spike masks, so each GEMM becomes ONE
// batched event-walk with 25 select-adds per active row (bitwise == dense
// ascending-i FMA chain; skipped terms are exact fma(w,0,acc) no-ops).
// GEMM1 keeps OpenBLAS SkylakeX K-blocking (8 x Kc=320); GEMM2/3 K=256<=320.
__global__ __launch_bounds__(256) void k1_fused(
    const float* __restrict__ obs, const float* __restrict__ emean, const float* __restrict__ estd,
    const float* __restrict__ w1t, const float* __restrict__ w2t, const float* __restrict__ w3t,
    const float* __restrict__ b1, const float* __restrict__ b2, const float* __restrict__ b3,
    const float* __restrict__ dw, const float* __restrict__ db, float* __restrict__ out)
{
    __shared__ __align__(16) uint32_t maskL[NIN];   // 10240 B: encoder spike masks
    __shared__ __align__(16) uint32_t maskS1[H];    //  1024 B: layer-1 spike masks
    __shared__ __align__(16) uint32_t maskS2[H];    //  1024 B: layer-2 spike masks
    __shared__ float cnt3[OUTP];

    const int tid = threadIdx.x;
    const int b = blockIdx.x;

    // ---- Phase A: population encoding, numpy-faithful fp32 op-by-op ----
    for (int k = 0; k < 10; ++k) {
        int i = k * 256 + tid;
        int o = i / 10;
        float x  = obs[b * OBSD + o];
        float mu = emean[i];
        float sd = estd[i];
        float d  = __fadd_rn(x, -mu);
        float d2 = __fmul_rn(d, d);
        float nm = __fmul_rn(-0.5f, d2);
        float dn = __fmul_rn(sd, sd);
        float a  = exp_cr(__fdiv_rn(nm, dn));
        float volt = 0.0f;
        uint32_t m = 0;
        #pragma unroll
        for (int t = 0; t < TS; ++t) {
            volt = __fadd_rn(volt, a);
            if (volt > 0.999f) { m |= (1u << t); volt = __fadd_rn(volt, -0.999f); }
        }
        maskL[i] = m;
    }
    __syncthreads();

    // ---- Phase B: event GEMM1, K-blocks {320 x 8} left-assoc (validated) ----
    float acc[TS];
    #pragma unroll
    for (int t = 0; t < TS; ++t) acc[t] = 0.0f;

    const uint4* mq = (const uint4*)maskL;
    for (int blk = 0; blk < 8; ++blk) {
        float part[TS];
        #pragma unroll
        for (int t = 0; t < TS; ++t) part[t] = 0.0f;

        for (int c = blk * 80; c < blk * 80 + 80; ++c) {   // 320 inputs = 80 uint4
            uint4 mm = mq[c];   // block-uniform broadcast read
            #pragma unroll
            for (int u = 0; u < 4; ++u) {
                uint32_t m = (uint32_t)__builtin_amdgcn_readfirstlane((int)((&mm.x)[u]));
                if (m) {
                    int i = c * 4 + u;
                    float w = w1t[(size_t)i * H + tid];   // coalesced
                    #pragma unroll
                    for (int t = 0; t < TS; ++t)
                        part[t] = __fadd_rn(part[t], (m & (1u << t)) ? w : 0.0f);
                }
            }
        }
        #pragma unroll
        for (int t = 0; t < TS; ++t) acc[t] = __fadd_rn(acc[t], part[t]);
    }

    // ---- Phase C1: layer-1 LIF, all 25 steps (acc stays in VGPRs) ----
    {
        const float b1v = b1[tid];
        float c1 = 0, v1 = 0, s1 = 0;
        uint32_t m1 = 0;
        #pragma unroll
        for (int t = 0; t < TS; ++t) {
            lif_step(acc[t], b1v, c1, v1, s1);
            if (s1 != 0.0f) m1 |= (1u << t);
        }
        maskS1[tid] = m1;
    }
    __syncthreads();

    // ---- Phase C2: batched GEMM2 (one walk, 25 select-adds per active row) ----
    float acc2[TS];
    #pragma unroll
    for (int t = 0; t < TS; ++t) acc2[t] = 0.0f;
    {
        const uint4* mq1 = (const uint4*)maskS1;
        for (int c = 0; c < H / 4; ++c) {
            uint4 mm = mq1[c];
            #pragma unroll
            for (int u = 0; u < 4; ++u) {
                uint32_t m = (uint32_t)__builtin_amdgcn_readfirstlane((int)((&mm.x)[u]));
                if (m) {
                    int i = c * 4 + u;
                    float w = w2t[i * H + tid];
                    #pragma unroll
                    for (int t = 0; t < TS; ++t)
                        acc2[t] = __fadd_rn(acc2[t], (m & (1u << t)) ? w : 0.0f);
                }
            }
        }
        // layer-2 LIF, all 25 steps
        const float b2v = b2[tid];
        float c2 = 0, v2 = 0, s2 = 0;
        uint32_t m2 = 0;
        #pragma unroll
        for (int t = 0; t < TS; ++t) {
            lif_step(acc2[t], b2v, c2, v2, s2);
            if (s2 != 0.0f) m2 |= (1u << t);
        }
        maskS2[tid] = m2;
    }
    __syncthreads();

    // ---- Phase C3: batched GEMM3 + layer-3 LIF (threads 0..79) ----
    if (tid < OUTP) {
        float x3[TS];
        #pragma unroll
        for (int t = 0; t < TS; ++t) x3[t] = 0.0f;
        const uint4* mq2 = (const uint4*)maskS2;
        for (int c = 0; c < H / 4; ++c) {
            uint4 mm = mq2[c];
            #pragma unroll
            for (int u = 0; u < 4; ++u) {
                uint32_t m = (uint32_t)__builtin_amdgcn_readfirstlane((int)((&mm.x)[u]));
                if (m) {
                    int i = c * 4 + u;
                    float w = w3t[i * OUTP + tid];
                    #pragma unroll
                    for (int t = 0; t < TS; ++t)
                        x3[t] = __fadd_rn(x3[t], (m & (1u << t)) ? w : 0.0f);
                }
            }
        }
        const float b3v = b3[tid];
        float c3 = 0, v3 = 0, s3 = 0, ct = 0;
        #pragma unroll
        for (int t = 0; t < TS; ++t) {
            lif_step(x3[t], b3v, c3, v3, s3);
            ct += s3;
        }
        cnt3[tid] = ct;
    }
    __syncthreads();

    // ---- decode: per-op rounding like np einsum (no FMA) ----
    if (tid < 8) {
        float raw = 0.0f;
        #pragma unroll
        for (int pp = 0; pp < POP; ++pp) {
            float po = __fdiv_rn(cnt3[tid * POP + pp], 25.0f);
            raw = __fadd_rn(raw, __fmul_rn(po, dw[tid * POP + pp]));
        }
        raw = __fadd_rn(raw, db[tid]);
        out[b * 8 + tid] = (float)tanh((double)raw);
    }
}

extern "C" void kernel_launch(void* const* d_in, const int* in_sizes, int n_in,
                              void* d_out, int out_size, void* d_ws, size_t ws_size,
                              hipStream_t stream) {
    const float* obs   = (const float*)d_in[0];
    const float* emean = (const float*)d_in[1];
    const float* estd  = (const float*)d_in[2];
    const float* w1    = (const float*)d_in[3];
    const float* b1    = (const float*)d_in[4];
    const float* w2    = (const float*)d_in[5];
    const float* b2    = (const float*)d_in[6];
    const float* w3    = (const float*)d_in[7];
    const float* b3    = (const float*)d_in[8];
    const float* dw    = (const float*)d_in[9];
    const float* db    = (const float*)d_in[10];
    float* out = (float*)d_out;

    char* ws = (char*)d_ws;
    float* w1t = (float*)(ws);                 // 655360 * 4 = 2,621,440 B
    float* w2t = (float*)(ws + 2621440);       //  65536 * 4 =   262,144 B
    float* w3t = (float*)(ws + 2883584);       //  20480 * 4 =    81,920 B

    k0_transpose<<<2896, 256, 0, stream>>>(w1, w2, w3, w1t, w2t, w3t);
    k1_fused<<<NB, 256, 0, stream>>>(obs, emean, estd, w1t, w2t, w3t,
                                     b1, b2, b3, dw, db, out);
}

// Round 12
// 492.831 us; speedup vs baseline: 1.7987x; 1.7987x over previous
//
#include <hip/hip_runtime.h>
#include <stdint.h>

#define NB 2048
#define OBSD 256
#define POP 10
#define NIN 2560       // OBS_DIM * POP_DIM
#define H 256          // HID1 == HID2
#define OUTP 80        // ACT_DIM * DE_POP
#define TS 25
#define RECF 28        // floats per row record (25 bit-floats + 3 pad, 112 B)

// correctly-rounded fp32 exp (fp64 exp then round) — matches SVML high-accuracy
// expf that numpy dispatches to on AVX512 hosts (validated r8: absmax 4.8e-7).
__device__ __forceinline__ float exp_cr(float x) {
    return (float)exp((double)x);
}

__device__ __forceinline__ int rfl(int v) {
    return __builtin_amdgcn_readfirstlane(v);
}

// ---------------- K0: transpose weights into fp32 [k][n] layouts in ws ----------------
__global__ __launch_bounds__(256) void k0_transpose(
    const float* __restrict__ w1, const float* __restrict__ w2, const float* __restrict__ w3,
    float* __restrict__ w1t, float* __restrict__ w2t, float* __restrict__ w3t)
{
    int idx = blockIdx.x * 256 + threadIdx.x;
    const int N1 = NIN * H;       // 655360
    const int N2 = H * H;         // 65536
    const int N3 = H * OUTP;      // 20480
    if (idx < N1) {
        int i = idx >> 8, j = idx & 255;
        w1t[idx] = w1[j * NIN + i];
    } else if (idx < N1 + N2) {
        int k = idx - N1;
        int i = k >> 8, j = k & 255;
        w2t[k] = w2[j * H + i];
    } else if (idx < N1 + N2 + N3) {
        int k = idx - N1 - N2;
        int i = k / OUTP, j = k - i * OUTP;
        w3t[k] = w3[j * H + i];
    }
}

// One LIF step, numpy-faithful per-op rounding (no contraction):
__device__ __forceinline__ void lif_step(float x, float bv, float& c, float& v, float& s) {
    float cn = __fadd_rn(__fadd_rn(__fmul_rn(c, 0.5f), x), bv);
    c = cn;
    float vp = v;
    float t  = __fmul_rn(__fmul_rn(vp, 0.75f), __fadd_rn(1.0f, -s));
    float vn = __fadd_rn(t, cn);
    float ag = __fdiv_rn(__fadd_rn(vp, -vn), 3.0f);
    float ex = exp_cr(ag);
    float vth = __fadd_rn(0.25f, __fmul_rn(0.5f, __fadd_rn(ex, -1.0f)));
    v = vn;
    s = (vn > vth) ? 1.0f : 0.0f;
}

// write one row record: 25 spike bits as floats {0.0,1.0} + 3 pad (7 float4s)
__device__ __forceinline__ void write_rec(float* __restrict__ pairL, int pos, uint32_t m) {
    float f[RECF];
    #pragma unroll
    for (int t = 0; t < TS; ++t) f[t] = (m >> t) & 1u ? 1.0f : 0.0f;
    f[25] = 0.0f; f[26] = 0.0f; f[27] = 0.0f;
    float4* dst = (float4*)&pairL[pos * RECF];
    #pragma unroll
    for (int p = 0; p < 7; ++p)
        dst[p] = make_float4(f[4 * p], f[4 * p + 1], f[4 * p + 2], f[4 * p + 3]);
}

// 25-term fma chain: acc[t] = fma(w, bit[t], acc[t])  (bitwise == BLAS's
// fma(w, s, acc) with s in {0,1}; == r8-r11's validated select-add chain)
__device__ __forceinline__ void fma25(float w, const float* __restrict__ rec,
                                      float* __restrict__ acc) {
    #pragma unroll
    for (int t = 0; t < TS; ++t) acc[t] = fmaf(w, rec[t], acc[t]);
}

// ---------------- K1: fused, ONE batch row per block (2048 blocks) ----------------
__global__ __launch_bounds__(256, 4) void k1_fused(
    const float* __restrict__ obs, const float* __restrict__ emean, const float* __restrict__ estd,
    const float* __restrict__ w1t, const float* __restrict__ w2t, const float* __restrict__ w3t,
    const float* __restrict__ b1, const float* __restrict__ b2, const float* __restrict__ b3,
    const float* __restrict__ dw, const float* __restrict__ db, float* __restrict__ out)
{
    __shared__ __align__(16) float pairL[256 * RECF];  // 28,672 B row records
    __shared__ __align__(16) int   idxL[256];          //  1,024 B premult indices
    __shared__ uint32_t waveCnt[4];
    __shared__ float cnt3[OUTP];

    const int tid = threadIdx.x;
    const int wave = tid >> 6, lane = tid & 63;
    const int b = blockIdx.x;
    const unsigned long long below = (1ull << lane) - 1ull;

    // ---- Phase A: population encoding, numpy-faithful fp32 op-by-op ----
    uint32_t msk[10];
    #pragma unroll
    for (int k = 0; k < 10; ++k) {
        int i = k * 256 + tid;
        int o = i / 10;
        float x  = obs[b * OBSD + o];
        float mu = emean[i];
        float sd = estd[i];
        float d  = __fadd_rn(x, -mu);
        float d2 = __fmul_rn(d, d);
        float nm = __fmul_rn(-0.5f, d2);
        float dn = __fmul_rn(sd, sd);
        float a  = exp_cr(__fdiv_rn(nm, dn));
        float volt = 0.0f;
        uint32_t m = 0;
        #pragma unroll
        for (int t = 0; t < TS; ++t) {
            volt = __fadd_rn(volt, a);
            if (volt > 0.999f) { m |= (1u << t); volt = __fadd_rn(volt, -0.999f); }
        }
        msk[k] = m;
    }

    // ---- Phase B: event GEMM1 in two halves (<=256 active rows per half:
    // a-window covers at most 2 receptive fields per obs dim). K-blocks
    // {320 x 8} left-assoc via sorted-index boundary folds (validated r8). ----
    float acc[TS], part[TS];
    #pragma unroll
    for (int t = 0; t < TS; ++t) { acc[t] = 0.0f; part[t] = 0.0f; }
    int nextB = 320 * H;

    for (int h = 0; h < 2; ++h) {
        // build compacted records (ascending i) for this half
        int runTot = 0;
        for (int kk = 0; kk < 5; ++kk) {
            int k = h * 5 + kk;
            uint32_t m = msk[k];
            unsigned long long bal = __ballot(m != 0u);
            if (lane == 0) waveCnt[wave] = (uint32_t)__popcll(bal);
            __syncthreads();
            int base = runTot, tot = 0;
            #pragma unroll
            for (int w = 0; w < 4; ++w) {
                if (w < wave) base += (int)waveCnt[w];
                tot += (int)waveCnt[w];
            }
            if (m) {
                int pos = base + (int)__popcll(bal & below);
                idxL[pos] = (k * 256 + tid) * H;
                write_rec(pairL, pos, m);
            }
            runTot += tot;
            __syncthreads();
        }
        const int nAct = runTot;

        // walk: prefetch next row's weight; 25-fma chain per row
        int idxA = (nAct > 0) ? rfl(idxL[0]) : 0;
        float wA = (nAct > 0) ? w1t[idxA + tid] : 0.0f;
        for (int j = 0; j < nAct; ++j) {
            int idxCur = idxA;
            float wCur = wA;
            if (j + 1 < nAct) { idxA = rfl(idxL[j + 1]); wA = w1t[idxA + tid]; }
            while (idxCur >= nextB) {       // K-block boundary fold
                #pragma unroll
                for (int t = 0; t < TS; ++t) {
                    acc[t] = __fadd_rn(acc[t], part[t]);
                    part[t] = 0.0f;
                }
                nextB += 320 * H;
            }
            fma25(wCur, &pairL[j * RECF], part);
        }
        __syncthreads();   // records dead; next half (or C1 build) may overwrite
    }
    // final fold (remaining partial; empty trailing blocks are exact no-ops)
    #pragma unroll
    for (int t = 0; t < TS; ++t) acc[t] = __fadd_rn(acc[t], part[t]);

    // ---- C1: layer-1 LIF, all 25 steps; build layer-1 spike records ----
    uint32_t m1 = 0;
    {
        const float b1v = b1[tid];
        float c1 = 0, v1 = 0, s1 = 0;
        #pragma unroll
        for (int t = 0; t < TS; ++t) {
            lif_step(acc[t], b1v, c1, v1, s1);
            if (s1 != 0.0f) m1 |= (1u << t);
        }
    }
    unsigned long long bal = __ballot(m1 != 0u);
    if (lane == 0) waveCnt[wave] = (uint32_t)__popcll(bal);
    __syncthreads();
    int base1 = 0, n1 = 0;
    #pragma unroll
    for (int w = 0; w < 4; ++w) {
        if (w < wave) base1 += (int)waveCnt[w];
        n1 += (int)waveCnt[w];
    }
    if (m1) {
        int pos = base1 + (int)__popcll(bal & below);
        idxL[pos] = tid * H;
        write_rec(pairL, pos, m1);
    }
    __syncthreads();

    // ---- C2: batched GEMM2 walk (K=256, single block) + layer-2 LIF ----
    float acc2[TS];
    #pragma unroll
    for (int t = 0; t < TS; ++t) acc2[t] = 0.0f;
    {
        int idxA = (n1 > 0) ? rfl(idxL[0]) : 0;
        float wA = (n1 > 0) ? w2t[idxA + tid] : 0.0f;
        for (int j = 0; j < n1; ++j) {
            int   idxCur = idxA;
            float wCur = wA;
            if (j + 1 < n1) { idxA = rfl(idxL[j + 1]); wA = w2t[idxA + tid]; }
            (void)idxCur;
            fma25(wCur, &pairL[j * RECF], acc2);
        }
    }
    uint32_t m2 = 0;
    {
        const float b2v = b2[tid];
        float c2 = 0, v2 = 0, s2 = 0;
        #pragma unroll
        for (int t = 0; t < TS; ++t) {
            lif_step(acc2[t], b2v, c2, v2, s2);
            if (s2 != 0.0f) m2 |= (1u << t);
        }
    }
    __syncthreads();   // C2 walk reads done before list-2 build overwrites
    bal = __ballot(m2 != 0u);
    if (lane == 0) waveCnt[wave] = (uint32_t)__popcll(bal);
    __syncthreads();
    int base2 = 0, n2 = 0;
    #pragma unroll
    for (int w = 0; w < 4; ++w) {
        if (w < wave) base2 += (int)waveCnt[w];
        n2 += (int)waveCnt[w];
    }
    if (m2) {
        int pos = base2 + (int)__popcll(bal & below);
        idxL[pos] = tid * OUTP;
        write_rec(pairL, pos, m2);
    }
    __syncthreads();

    // ---- C3: batched GEMM3 walk + layer-3 LIF (threads 0..79) ----
    if (tid < OUTP) {
        float x3[TS];
        #pragma unroll
        for (int t = 0; t < TS; ++t) x3[t] = 0.0f;
        int idxA = (n2 > 0) ? rfl(idxL[0]) : 0;
        float wA = (n2 > 0) ? w3t[idxA + tid] : 0.0f;
        for (int j = 0; j < n2; ++j) {
            float wCur = wA;
            if (j + 1 < n2) { idxA = rfl(idxL[j + 1]); wA = w3t[idxA + tid]; }
            fma25(wCur, &pairL[j * RECF], x3);
        }
        const float b3v = b3[tid];
        float c3 = 0, v3 = 0, s3 = 0, ct = 0;
        #pragma unroll
        for (int t = 0; t < TS; ++t) {
            lif_step(x3[t], b3v, c3, v3, s3);
            ct += s3;
        }
        cnt3[tid] = ct;
    }
    __syncthreads();

    // ---- decode: per-op rounding like np einsum (no FMA) ----
    if (tid < 8) {
        float raw = 0.0f;
        #pragma unroll
        for (int pp = 0; pp < POP; ++pp) {
            float po = __fdiv_rn(cnt3[tid * POP + pp], 25.0f);
            raw = __fadd_rn(raw, __fmul_rn(po, dw[tid * POP + pp]));
        }
        raw = __fadd_rn(raw, db[tid]);
        out[b * 8 + tid] = (float)tanh((double)raw);
    }
}

extern "C" void kernel_launch(void* const* d_in, const int* in_sizes, int n_in,
                              void* d_out, int out_size, void* d_ws, size_t ws_size,
                              hipStream_t stream) {
    const float* obs   = (const float*)d_in[0];
    const float* emean = (const float*)d_in[1];
    const float* estd  = (const float*)d_in[2];
    const float* w1    = (const float*)d_in[3];
    const float* b1    = (const float*)d_in[4];
    const float* w2    = (const float*)d_in[5];
    const float* b2    = (const float*)d_in[6];
    const float* w3    = (const float*)d_in[7];
    const float* b3    = (const float*)d_in[8];
    const float* dw    = (const float*)d_in[9];
    const float* db    = (const float*)d_in[10];
    float* out = (float*)d_out;

    char* ws = (char*)d_ws;
    float* w1t = (float*)(ws);                 // 655360 * 4 = 2,621,440 B
    float* w2t = (float*)(ws + 2621440);       //  65536 * 4 =   262,144 B
    float* w3t = (float*)(ws + 2883584);       //  20480 * 4 =    81,920 B

    k0_transpose<<<2896, 256, 0, stream>>>(w1, w2, w3, w1t, w2t, w3t);
    k1_fused<<<NB, 256, 0, stream>>>(obs, emean, estd, w1t, w2t, w3t,
                                     b1, b2, b3, dw, db, out);
}